// Round 6
// baseline (178.092 us; speedup 1.0000x reference)
//
#include <hip/hip_runtime.h>
#include <hip/hip_bf16.h>

#define NPIX 196608
#define CIN  32
#define COUT 64
#define KNB  9
#define BATCH 4

typedef short short8 __attribute__((ext_vector_type(8)));
typedef float f32x4  __attribute__((ext_vector_type(4)));

static __device__ __forceinline__ unsigned short f2bf(float f) {
    union { float f; unsigned int u; } v; v.f = f;
    unsigned int r = v.u + 0x7FFFu + ((v.u >> 16) & 1u);   // RNE
    return (unsigned short)(r >> 16);
}

// ---------------------------------------------------------------------------
// Kernel 1: pack W (COUT,CIN,K) fp32 -> bf16 in MFMA A-fragment order.
// Wp[((k*4+m)*64 + lane)*8 + j] = bf16( W[o=m*16+(lane&15)][c=(lane>>4)*8+j][k] )
// Parallel: 72 blocks x 256 threads, one element each.
// ---------------------------------------------------------------------------
__global__ __launch_bounds__(256) void wpack_kernel(const float* __restrict__ W,
                                                    unsigned short* __restrict__ Wp) {
    int e = blockIdx.x * 256 + threadIdx.x;
    if (e >= 18432) return;
    int j = e & 7;
    int l = (e >> 3) & 63;
    int m = (e >> 9) & 3;
    int k = e >> 11;                       // 0..8
    int o = m * 16 + (l & 15);
    int c = ((l >> 4) << 3) + j;
    Wp[e] = f2bf(W[(o * CIN + c) * KNB + k]);
}

// ---------------------------------------------------------------------------
// Kernel 2: transpose+convert x (B,CIN,NPIX) fp32 -> xT (B,NPIX,CIN) bf16.
// ---------------------------------------------------------------------------
__global__ __launch_bounds__(256) void xpose_kernel(const float* __restrict__ x,
                                                    unsigned short* __restrict__ xT) {
    __shared__ unsigned int lds[64][17];
    int t   = threadIdx.x;
    int bid = blockIdx.x;                // 0 .. 4*3072-1
    int b   = bid / 3072;
    int pt  = bid - b * 3072;
    int p0  = pt * 64;

    #pragma unroll
    for (int i = 0; i < 4; ++i) {
        int e  = i * 256 + t;            // 0..1023
        int c2 = e >> 6;                 // channel pair 0..15
        int pp = e & 63;
        const float* xr = x + ((size_t)(b * CIN + 2 * c2)) * NPIX + p0 + pp;
        float lo = xr[0];
        float hi = xr[NPIX];
        lds[pp][c2] = (unsigned int)f2bf(lo) | ((unsigned int)f2bf(hi) << 16);
    }
    __syncthreads();
    #pragma unroll
    for (int i = 0; i < 4; ++i) {
        int e  = i * 256 + t;
        int pp = e >> 4;
        int c2 = e & 15;
        ((unsigned int*)xT)[((size_t)b * NPIX + p0 + pp) * 16 + c2] = lds[pp][c2];
    }
}

// ---------------------------------------------------------------------------
// Kernel 3: main gather + MFMA GEMM.
// Per block: batch b, 256-pixel tile. 4 waves; wave w owns pixels
// [w*64, w*64+64) x all 64 COUT. K-dim = 9 neighbors x 32 channels.
// W fragments read directly from global Wp (L2-hot, shared by all blocks) —
// LDS holds only the 9 KB index tile, so 4 blocks/CU instead of 3, and
// __launch_bounds__(256,4) caps VGPR at 128 for 16 waves/CU.
// ---------------------------------------------------------------------------
template <bool TR>
__global__ __launch_bounds__(256, 4) void conv_kernel(const unsigned short* __restrict__ xT,
                                                      const float* __restrict__ x,
                                                      const int* __restrict__ nbr,
                                                      const unsigned short* __restrict__ Wp,
                                                      const float* __restrict__ bias,
                                                      float* __restrict__ out) {
    __shared__ int ilds[2304];               // 9 KB: 256 px * 9 nbrs

    int t   = threadIdx.x;
    int bid = blockIdx.x;                    // 0..3071
    int b   = bid / 768;
    int pt  = bid - b * 768;
    int p0  = pt * 256;

    // stage neighbor indices (pre-scaled to byte offsets for TR path)
    for (int i = t; i < 2304; i += 256) {
        int idx = nbr[p0 * KNB + i];
        ilds[i] = TR ? (idx << 6) : idx;     // *64B row stride of xT
    }
    __syncthreads();

    int lane = t & 63;
    int wave = t >> 6;
    int r    = lane & 15;
    int q    = lane >> 4;
    int nb   = wave * 64;

    f32x4 acc[4][4] = {};                    // [m-tile][n-frag]

    const char* xb = (const char*)xT + ((size_t)b * NPIX) * 64 + q * 16;
    const unsigned short* wl = Wp + (size_t)lane * 8;

    int prow[4];
    #pragma unroll
    for (int f = 0; f < 4; ++f) prow[f] = (nb + f * 16 + r) * KNB;

    #pragma unroll 3
    for (int k = 0; k < KNB; ++k) {
        short8 bfrag[4];
        #pragma unroll
        for (int f = 0; f < 4; ++f) {
            int off = ilds[prow[f] + k];
            if (TR) {
                bfrag[f] = *(const short8*)(xb + off);
            } else {
                const float* xc = x + (size_t)(b * CIN + q * 8) * NPIX + off;
                #pragma unroll
                for (int j = 0; j < 8; ++j)
                    bfrag[f][j] = (short)f2bf(xc[(size_t)j * NPIX]);
            }
        }
        short8 afr[4];
        #pragma unroll
        for (int m = 0; m < 4; ++m)
            afr[m] = *(const short8*)(wl + (((k << 2) | m) << 9));   // ((k*4+m)*64)*8
        #pragma unroll
        for (int m = 0; m < 4; ++m)
            #pragma unroll
            for (int f = 0; f < 4; ++f)
                acc[m][f] = __builtin_amdgcn_mfma_f32_16x16x32_bf16(
                                afr[m], bfrag[f], acc[m][f], 0, 0, 0);
    }

    // epilogue: D col = lane&15 -> pixel, row = q*4+reg within 16 -> cout
    float* ob = out + (size_t)b * COUT * NPIX + p0 + nb + r;
    #pragma unroll
    for (int m = 0; m < 4; ++m) {
        f32x4 bv = *(const f32x4*)(bias + m * 16 + q * 4);
        #pragma unroll
        for (int rr = 0; rr < 4; ++rr) {
            float* orow = ob + (size_t)(m * 16 + q * 4 + rr) * NPIX;
            #pragma unroll
            for (int f = 0; f < 4; ++f)
                orow[f * 16] = acc[m][f][rr] + bv[rr];
        }
    }
}

// ---------------------------------------------------------------------------
extern "C" void kernel_launch(void* const* d_in, const int* in_sizes, int n_in,
                              void* d_out, int out_size, void* d_ws, size_t ws_size,
                              hipStream_t stream) {
    const float* x    = (const float*)d_in[0];
    const int*   nbr  = (const int*)d_in[1];
    const float* W    = (const float*)d_in[2];
    const float* bias = (const float*)d_in[3];
    float*       out  = (float*)d_out;

    const size_t wp_bytes = 18432 * sizeof(unsigned short);           // 36,864
    const size_t wp_pad   = (wp_bytes + 255) & ~(size_t)255;
    const size_t xT_bytes = (size_t)BATCH * NPIX * CIN * 2;           // ~50.3 MB

    unsigned short* Wp = (unsigned short*)d_ws;
    unsigned short* xT = (unsigned short*)((char*)d_ws + wp_pad);

    bool full = ws_size >= wp_pad + xT_bytes;

    wpack_kernel<<<72, 256, 0, stream>>>(W, Wp);
    if (full) {
        xpose_kernel<<<BATCH * (NPIX / 64), 256, 0, stream>>>(x, xT);
        conv_kernel<true><<<BATCH * (NPIX / 256), 256, 0, stream>>>(xT, x, nbr, Wp, bias, out);
    } else {
        conv_kernel<false><<<BATCH * (NPIX / 256), 256, 0, stream>>>(xT, x, nbr, Wp, bias, out);
    }
}

// Round 7
// 150.757 us; speedup vs baseline: 1.1813x; 1.1813x over previous
//
#include <hip/hip_runtime.h>
#include <hip/hip_bf16.h>

#define NPIX 196608
#define CIN  32
#define COUT 64
#define KNB  9
#define BATCH 4

typedef short short8 __attribute__((ext_vector_type(8)));
typedef float f32x4  __attribute__((ext_vector_type(4)));

static __device__ __forceinline__ unsigned short f2bf(float f) {
    union { float f; unsigned int u; } v; v.f = f;
    unsigned int r = v.u + 0x7FFFu + ((v.u >> 16) & 1u);   // RNE
    return (unsigned short)(r >> 16);
}

// ---------------------------------------------------------------------------
// Kernel 1: pack W (COUT,CIN,K) fp32 -> bf16 in MFMA A-fragment order.
// Wp[((k*4+m)*64 + lane)*8 + j] = bf16( W[o=m*16+(lane&15)][c=(lane>>4)*8+j][k] )
// ---------------------------------------------------------------------------
__global__ __launch_bounds__(256) void wpack_kernel(const float* __restrict__ W,
                                                    unsigned short* __restrict__ Wp) {
    int e = blockIdx.x * 256 + threadIdx.x;
    if (e >= 18432) return;
    int j = e & 7;
    int l = (e >> 3) & 63;
    int m = (e >> 9) & 3;
    int k = e >> 11;                       // 0..8
    int o = m * 16 + (l & 15);
    int c = ((l >> 4) << 3) + j;
    Wp[e] = f2bf(W[(o * CIN + c) * KNB + k]);
}

// ---------------------------------------------------------------------------
// Kernel 2: transpose+convert x (B,CIN,NPIX) fp32 -> xT pixel-major:
// xT[p][b][c] bf16 — 256 B per pixel = [b0 c0..31][b1 c0..31][b2..][b3..].
// Block = 64 pixels, all batches. LDS [64][65] uints (uint = 2 packed bf16).
// Stores are fully contiguous 4 KB per iter.
// ---------------------------------------------------------------------------
__global__ __launch_bounds__(256) void xpose_kernel(const float* __restrict__ x,
                                                    unsigned short* __restrict__ xT) {
    __shared__ unsigned int lds[64][65];     // [pp][slot], slot = b*16+c2
    int t  = threadIdx.x;
    int p0 = blockIdx.x * 64;                // 3072 blocks

    #pragma unroll
    for (int b = 0; b < 4; ++b) {
        #pragma unroll
        for (int i = 0; i < 4; ++i) {
            int e  = i * 256 + t;            // 0..1023
            int c2 = e >> 6;                 // channel pair 0..15
            int pp = e & 63;
            const float* xr = x + ((size_t)(b * CIN + 2 * c2)) * NPIX + p0 + pp;
            lds[pp][b * 16 + c2] =
                (unsigned int)f2bf(xr[0]) | ((unsigned int)f2bf(xr[NPIX]) << 16);
        }
    }
    __syncthreads();
    unsigned int* dst = (unsigned int*)xT + (size_t)p0 * 64;
    #pragma unroll
    for (int i = 0; i < 16; ++i) {
        int u = i * 256 + t;                 // 0..4095, contiguous
        dst[u] = lds[u >> 6][u & 63];
    }
}

// ---------------------------------------------------------------------------
// Kernel 3: main gather + MFMA GEMM, batch-fused.
// Block = 64 pixels x ALL 4 batches; wave w handles batch w.
// Indices staged ONCE per pixel tile (576 ints). Gathers for one (px,nbr)
// from the 4 waves hit one contiguous 256 B pixel block.
// W fragments from global Wp (L2-hot). Epilogue: 16 consecutive px per frag.
// ---------------------------------------------------------------------------
template <bool TR>
__global__ __launch_bounds__(256, 4) void conv_kernel(const unsigned short* __restrict__ xT,
                                                      const float* __restrict__ x,
                                                      const int* __restrict__ nbr,
                                                      const unsigned short* __restrict__ Wp,
                                                      const float* __restrict__ bias,
                                                      float* __restrict__ out) {
    __shared__ int ilds[576];                // 64 px * 9 nbrs

    int t  = threadIdx.x;
    int p0 = blockIdx.x * 64;                // 3072 blocks

    for (int i = t; i < 576; i += 256) {
        int idx = nbr[p0 * KNB + i];
        ilds[i] = TR ? (idx << 8) : idx;     // *256B pixel block
    }
    __syncthreads();

    int lane = t & 63;
    int w    = t >> 6;                       // wave = batch
    int r    = lane & 15;
    int q    = lane >> 4;

    f32x4 acc[4][4] = {};                    // [m-tile][px-frag]

    const char* xb = (const char*)xT + w * 64 + q * 16;
    const unsigned short* wl = Wp + (size_t)lane * 8;

    int prow[4];
    #pragma unroll
    for (int f = 0; f < 4; ++f) prow[f] = (f * 16 + r) * KNB;

    #pragma unroll 3
    for (int k = 0; k < KNB; ++k) {
        short8 bfrag[4];
        #pragma unroll
        for (int f = 0; f < 4; ++f) {
            int off = ilds[prow[f] + k];
            if (TR) {
                bfrag[f] = *(const short8*)(xb + off);
            } else {
                const float* xc = x + (size_t)(w * CIN + q * 8) * NPIX + off;
                #pragma unroll
                for (int j = 0; j < 8; ++j)
                    bfrag[f][j] = (short)f2bf(xc[(size_t)j * NPIX]);
            }
        }
        short8 afr[4];
        #pragma unroll
        for (int m = 0; m < 4; ++m)
            afr[m] = *(const short8*)(wl + (((k << 2) | m) << 9));   // ((k*4+m)*64)*8
        #pragma unroll
        for (int m = 0; m < 4; ++m)
            #pragma unroll
            for (int f = 0; f < 4; ++f)
                acc[m][f] = __builtin_amdgcn_mfma_f32_16x16x32_bf16(
                                afr[m], bfrag[f], acc[m][f], 0, 0, 0);
    }

    // epilogue: col r of frag f -> pixel p0 + f*16 + r; row q*4+rr -> cout
    float* ob = out + (size_t)w * COUT * NPIX + p0 + r;
    #pragma unroll
    for (int m = 0; m < 4; ++m) {
        f32x4 bv = *(const f32x4*)(bias + m * 16 + q * 4);
        #pragma unroll
        for (int rr = 0; rr < 4; ++rr) {
            float* orow = ob + (size_t)(m * 16 + q * 4 + rr) * NPIX;
            #pragma unroll
            for (int f = 0; f < 4; ++f)
                orow[f * 16] = acc[m][f][rr] + bv[rr];
        }
    }
}

// ---------------------------------------------------------------------------
extern "C" void kernel_launch(void* const* d_in, const int* in_sizes, int n_in,
                              void* d_out, int out_size, void* d_ws, size_t ws_size,
                              hipStream_t stream) {
    const float* x    = (const float*)d_in[0];
    const int*   nbr  = (const int*)d_in[1];
    const float* W    = (const float*)d_in[2];
    const float* bias = (const float*)d_in[3];
    float*       out  = (float*)d_out;

    const size_t wp_bytes = 18432 * sizeof(unsigned short);           // 36,864
    const size_t wp_pad   = (wp_bytes + 255) & ~(size_t)255;
    const size_t xT_bytes = (size_t)BATCH * NPIX * CIN * 2;           // ~50.3 MB

    unsigned short* Wp = (unsigned short*)d_ws;
    unsigned short* xT = (unsigned short*)((char*)d_ws + wp_pad);

    bool full = ws_size >= wp_pad + xT_bytes;

    wpack_kernel<<<72, 256, 0, stream>>>(W, Wp);
    if (full) {
        xpose_kernel<<<NPIX / 64, 256, 0, stream>>>(x, xT);
        conv_kernel<true><<<NPIX / 64, 256, 0, stream>>>(xT, x, nbr, Wp, bias, out);
    } else {
        conv_kernel<false><<<NPIX / 64, 256, 0, stream>>>(xT, x, nbr, Wp, bias, out);
    }
}

// Round 8
// 144.084 us; speedup vs baseline: 1.2360x; 1.0463x over previous
//
#include <hip/hip_runtime.h>
#include <hip/hip_bf16.h>

#define NPIX 196608
#define CIN  32
#define COUT 64
#define KNB  9
#define BATCH 4

typedef short short8 __attribute__((ext_vector_type(8)));
typedef float f32x4  __attribute__((ext_vector_type(4)));

static __device__ __forceinline__ unsigned short f2bf(float f) {
    union { float f; unsigned int u; } v; v.f = f;
    unsigned int r = v.u + 0x7FFFu + ((v.u >> 16) & 1u);   // RNE
    return (unsigned short)(r >> 16);
}

// ---------------------------------------------------------------------------
// Kernel 1: pack W (COUT,CIN,K) fp32 -> bf16 in MFMA A-fragment order.
// Wp[((k*4+m)*64 + lane)*8 + j] = bf16( W[o=m*16+(lane&15)][c=(lane>>4)*8+j][k] )
// ---------------------------------------------------------------------------
__global__ __launch_bounds__(256) void wpack_kernel(const float* __restrict__ W,
                                                    unsigned short* __restrict__ Wp) {
    int e = blockIdx.x * 256 + threadIdx.x;
    if (e >= 18432) return;
    int j = e & 7;
    int l = (e >> 3) & 63;
    int m = (e >> 9) & 3;
    int k = e >> 11;                       // 0..8
    int o = m * 16 + (l & 15);
    int c = ((l >> 4) << 3) + j;
    Wp[e] = f2bf(W[(o * CIN + c) * KNB + k]);
}

// ---------------------------------------------------------------------------
// Kernel 2: transpose+convert x (B,CIN,NPIX) fp32 -> xT pixel-major:
// xT[p][b][c] bf16 — 256 B per pixel. x loads are single-use -> nontemporal
// (don't pollute L2 ahead of conv's gather phase).
// ---------------------------------------------------------------------------
__global__ __launch_bounds__(256) void xpose_kernel(const float* __restrict__ x,
                                                    unsigned short* __restrict__ xT) {
    __shared__ unsigned int lds[64][65];     // [pp][slot], slot = b*16+c2
    int t  = threadIdx.x;
    int p0 = blockIdx.x * 64;                // 3072 blocks

    #pragma unroll
    for (int b = 0; b < 4; ++b) {
        #pragma unroll
        for (int i = 0; i < 4; ++i) {
            int e  = i * 256 + t;            // 0..1023
            int c2 = e >> 6;                 // channel pair 0..15
            int pp = e & 63;
            const float* xr = x + ((size_t)(b * CIN + 2 * c2)) * NPIX + p0 + pp;
            float lo = __builtin_nontemporal_load(xr);
            float hi = __builtin_nontemporal_load(xr + NPIX);
            lds[pp][b * 16 + c2] =
                (unsigned int)f2bf(lo) | ((unsigned int)f2bf(hi) << 16);
        }
    }
    __syncthreads();
    unsigned int* dst = (unsigned int*)xT + (size_t)p0 * 64;
    #pragma unroll
    for (int i = 0; i < 16; ++i) {
        int u = i * 256 + t;                 // 0..4095, contiguous
        dst[u] = lds[u >> 6][u & 63];
    }
}

// ---------------------------------------------------------------------------
// Kernel 3: main gather + MFMA GEMM, batch-fused.
// Block = 64 pixels x ALL 4 batches; wave w handles batch w.
// Output stores are NON-TEMPORAL: keep L2 reserved for the random
// gather-reuse working set (xT, reused ~9x/pixel) instead of letting the
// 197 MB streaming write evict it. nbr reads also nt (single-use).
// ---------------------------------------------------------------------------
template <bool TR>
__global__ __launch_bounds__(256, 4) void conv_kernel(const unsigned short* __restrict__ xT,
                                                      const float* __restrict__ x,
                                                      const int* __restrict__ nbr,
                                                      const unsigned short* __restrict__ Wp,
                                                      const float* __restrict__ bias,
                                                      float* __restrict__ out) {
    __shared__ int ilds[576];                // 64 px * 9 nbrs

    int t  = threadIdx.x;
    int p0 = blockIdx.x * 64;                // 3072 blocks

    for (int i = t; i < 576; i += 256) {
        int idx = __builtin_nontemporal_load(&nbr[p0 * KNB + i]);
        ilds[i] = TR ? (idx << 8) : idx;     // *256B pixel block
    }
    __syncthreads();

    int lane = t & 63;
    int w    = t >> 6;                       // wave = batch
    int r    = lane & 15;
    int q    = lane >> 4;

    f32x4 acc[4][4] = {};                    // [m-tile][px-frag]

    const char* xb = (const char*)xT + w * 64 + q * 16;
    const unsigned short* wl = Wp + (size_t)lane * 8;

    int prow[4];
    #pragma unroll
    for (int f = 0; f < 4; ++f) prow[f] = (f * 16 + r) * KNB;

    #pragma unroll 3
    for (int k = 0; k < KNB; ++k) {
        short8 bfrag[4];
        #pragma unroll
        for (int f = 0; f < 4; ++f) {
            int off = ilds[prow[f] + k];
            if (TR) {
                bfrag[f] = *(const short8*)(xb + off);
            } else {
                const float* xc = x + (size_t)(w * CIN + q * 8) * NPIX + off;
                #pragma unroll
                for (int j = 0; j < 8; ++j)
                    bfrag[f][j] = (short)f2bf(xc[(size_t)j * NPIX]);
            }
        }
        short8 afr[4];
        #pragma unroll
        for (int m = 0; m < 4; ++m)
            afr[m] = *(const short8*)(wl + (((k << 2) | m) << 9));   // ((k*4+m)*64)*8
        #pragma unroll
        for (int m = 0; m < 4; ++m)
            #pragma unroll
            for (int f = 0; f < 4; ++f)
                acc[m][f] = __builtin_amdgcn_mfma_f32_16x16x32_bf16(
                                afr[m], bfrag[f], acc[m][f], 0, 0, 0);
    }

    // epilogue: col r of frag f -> pixel p0 + f*16 + r; row q*4+rr -> cout
    float* ob = out + (size_t)w * COUT * NPIX + p0 + r;
    #pragma unroll
    for (int m = 0; m < 4; ++m) {
        f32x4 bv = *(const f32x4*)(bias + m * 16 + q * 4);
        #pragma unroll
        for (int rr = 0; rr < 4; ++rr) {
            float* orow = ob + (size_t)(m * 16 + q * 4 + rr) * NPIX;
            #pragma unroll
            for (int f = 0; f < 4; ++f)
                __builtin_nontemporal_store(acc[m][f][rr] + bv[rr], orow + f * 16);
        }
    }
}

// ---------------------------------------------------------------------------
extern "C" void kernel_launch(void* const* d_in, const int* in_sizes, int n_in,
                              void* d_out, int out_size, void* d_ws, size_t ws_size,
                              hipStream_t stream) {
    const float* x    = (const float*)d_in[0];
    const int*   nbr  = (const int*)d_in[1];
    const float* W    = (const float*)d_in[2];
    const float* bias = (const float*)d_in[3];
    float*       out  = (float*)d_out;

    const size_t wp_bytes = 18432 * sizeof(unsigned short);           // 36,864
    const size_t wp_pad   = (wp_bytes + 255) & ~(size_t)255;
    const size_t xT_bytes = (size_t)BATCH * NPIX * CIN * 2;           // ~50.3 MB

    unsigned short* Wp = (unsigned short*)d_ws;
    unsigned short* xT = (unsigned short*)((char*)d_ws + wp_pad);

    bool full = ws_size >= wp_pad + xT_bytes;

    wpack_kernel<<<72, 256, 0, stream>>>(W, Wp);
    if (full) {
        xpose_kernel<<<NPIX / 64, 256, 0, stream>>>(x, xT);
        conv_kernel<true><<<NPIX / 64, 256, 0, stream>>>(xT, x, nbr, Wp, bias, out);
    } else {
        conv_kernel<false><<<NPIX / 64, 256, 0, stream>>>(xT, x, nbr, Wp, bias, out);
    }
}